// Round 7
// baseline (53.470 us; speedup 1.0000x reference)
//
#include <hip/hip_runtime.h>
#include <hip/hip_bf16.h>

using f32x4   = __attribute__((ext_vector_type(4))) float;
using bf16x8  = __attribute__((ext_vector_type(8))) short;
using ushort8 = __attribute__((ext_vector_type(8))) unsigned short;

constexpr int N_ = 512;
constexpr int K_ = 512;
constexpr int LDSROW = 520;   // bf16 elems per LDS row: 512 + 8 pad (1040 B, 16B-aligned)

__device__ inline ushort f2bf(float f) {
  union { __hip_bfloat16 h; ushort u; } c;
  c.h = __float2bfloat16(f);
  return c.u;
}

// ---- pre-kernel: pack W[512][512] fp32 -> fragment-linear bf16 ----
// frag f = n_tile*16 + kc ; lane l holds W[n_tile*16 + (l&15)][kc*32 + (l>>4)*8 ..+8]
__global__ __launch_bounds__(256)
void pack_w(const float* __restrict__ W, ushort* __restrict__ P) {
  const int tau = blockIdx.x * 256 + threadIdx.x;   // 0..32767
  const int l = tau & 63, f = tau >> 6;
  const int row = (f >> 4) * 16 + (l & 15);
  const int kb  = (f & 15) * 32 + (l >> 4) * 8;
  const float* s = W + (size_t)row * K_ + kb;
  f32x4 v0 = *reinterpret_cast<const f32x4*>(s);
  f32x4 v1 = *reinterpret_cast<const f32x4*>(s + 4);
  ushort8 o;
  o[0] = f2bf(v0.x); o[1] = f2bf(v0.y); o[2] = f2bf(v0.z); o[3] = f2bf(v0.w);
  o[4] = f2bf(v1.x); o[5] = f2bf(v1.y); o[6] = f2bf(v1.z); o[7] = f2bf(v1.w);
  *reinterpret_cast<ushort8*>(P + (size_t)tau * 8) = o;
}

// ---- main GEMM: stage X once per wave, then LDS-resident compute ----
// 512 blocks (pure M partition), 4 waves/block, wave owns 16 rows x all N.
// Zero barriers: each wave's LDS slice is private.
__global__ __launch_bounds__(256, 2)
void gemm_pp(const float* __restrict__ X, const ushort* __restrict__ Wp,
             float* __restrict__ C) {
  __shared__ ushort As[4][16 * LDSROW];   // 66.5 KB/block

  const int t = threadIdx.x, lane = t & 63, wv = t >> 6;
  const int m0 = blockIdx.x * 64 + wv * 16;
  ushort* lds = &As[wv][0];

  const ushort* bp = Wp + lane * 8;
  const float*  xw = X + (size_t)m0 * K_;

  // ---- one-time X staging: 16 rows x 512 f32 -> bf16 LDS ----
  f32x4 xr[2][8];
  auto LDX = [&](int buf, int r) {
#pragma unroll
    for (int i = 0; i < 8; ++i)
      xr[buf][i] = *reinterpret_cast<const f32x4*>(xw + r * 2048 + i * 256 + lane * 4);
  };
  auto STX = [&](int buf, int r) {
#pragma unroll
    for (int i = 0; i < 8; ++i) {
      const int flat = r * 2048 + i * 256 + lane * 4;
      const int row = flat >> 9, col = flat & 511;
      ushort4 h;
      h.x = f2bf(xr[buf][i].x); h.y = f2bf(xr[buf][i].y);
      h.z = f2bf(xr[buf][i].z); h.w = f2bf(xr[buf][i].w);
      *reinterpret_cast<ushort4*>(&lds[row * LDSROW + col]) = h;
    }
  };

  bf16x8 b[3][8];
  auto LDB = [&](int buf, int s) {     // 8 frags for step s = bn*8 + ks
    const int bn = s >> 3, kc0 = (s & 7) * 2;
#pragma unroll
    for (int kk = 0; kk < 2; ++kk)
#pragma unroll
      for (int ni = 0; ni < 4; ++ni)
        b[buf][kk * 4 + ni] = *reinterpret_cast<const bf16x8*>(
            bp + (size_t)((bn * 4 + ni) * 16 + kc0 + kk) * 512);
  };

  // pipeline the staging (2-deep) and pre-issue B for s=0,1
  LDX(0, 0); LDX(1, 1);
  LDB(0, 0); LDB(1, 1);
  STX(0, 0); LDX(0, 2);
  STX(1, 1); LDX(1, 3);
  STX(0, 2); STX(1, 3);

  f32x4 acc[4] = {};
  const int arow = (lane & 15) * LDSROW;
  const int akof = (lane >> 4) * 8;
  const int rsub = (lane >> 4) * 4;

#pragma unroll
  for (int s = 0; s < 64; ++s) {
    const int ks = s & 7;
    if (s + 2 < 64) LDB((s + 2) % 3, s + 2);   // 2-deep B prefetch (L2-hot)

    bf16x8 a0 = *reinterpret_cast<const bf16x8*>(&lds[arow + ks * 64 + akof]);
    bf16x8 a1 = *reinterpret_cast<const bf16x8*>(&lds[arow + ks * 64 + 32 + akof]);
    const int cb = s % 3;
    acc[0] = __builtin_amdgcn_mfma_f32_16x16x32_bf16(a0, b[cb][0], acc[0], 0, 0, 0);
    acc[1] = __builtin_amdgcn_mfma_f32_16x16x32_bf16(a0, b[cb][1], acc[1], 0, 0, 0);
    acc[2] = __builtin_amdgcn_mfma_f32_16x16x32_bf16(a0, b[cb][2], acc[2], 0, 0, 0);
    acc[3] = __builtin_amdgcn_mfma_f32_16x16x32_bf16(a0, b[cb][3], acc[3], 0, 0, 0);
    acc[0] = __builtin_amdgcn_mfma_f32_16x16x32_bf16(a1, b[cb][4], acc[0], 0, 0, 0);
    acc[1] = __builtin_amdgcn_mfma_f32_16x16x32_bf16(a1, b[cb][5], acc[1], 0, 0, 0);
    acc[2] = __builtin_amdgcn_mfma_f32_16x16x32_bf16(a1, b[cb][6], acc[2], 0, 0, 0);
    acc[3] = __builtin_amdgcn_mfma_f32_16x16x32_bf16(a1, b[cb][7], acc[3], 0, 0, 0);

    if (ks == 7) {                       // finished bn: store 16x64 and reset
      const int bn = s >> 3;
      const int col0 = bn * 64 + (lane & 15);
#pragma unroll
      for (int ni = 0; ni < 4; ++ni) {
#pragma unroll
        for (int r = 0; r < 4; ++r)
          C[(size_t)(m0 + rsub + r) * N_ + (col0 + ni * 16)] = acc[ni][r];
        f32x4 z = {0.f, 0.f, 0.f, 0.f};
        acc[ni] = z;
      }
    }
  }
}

// ---- fallback (round-3 kernel) if ws is too small for the W pack ----
constexpr int FBM = 128, FBN = 128, FLDSK = 72, FNKS = 8;

__global__ __launch_bounds__(512, 4)
void gemm_fb(const float* __restrict__ X, const float* __restrict__ W,
             float* __restrict__ C) {
  __shared__ ushort Asf[2][FBM * FLDSK];
  __shared__ ushort Bsf[2][FBN * FLDSK];
  const int t = threadIdx.x, lane = t & 63, wave = t >> 6;
  const int wr = wave >> 2, wc = wave & 3;
  const int cpx = gridDim.x >> 3;
  const int bid = (blockIdx.x & 7) * cpx + (blockIdx.x >> 3);
  const int bn = bid & 3, bm = bid >> 2;
  const int m0 = bm * FBM, n0 = bn * FBN;
  const int sr = t >> 4, sc = (t & 15) * 4;
  const float* xp = X + (size_t)(m0 + sr) * K_ + sc;
  const float* wp = W + (size_t)(n0 + sr) * K_ + sc;
  f32x4 acc[4][2] = {};
  f32x4 ra[2][4], rb[2][4];
  auto LOAD = [&](int set, int ks) {
#pragma unroll
    for (int i = 0; i < 4; ++i) {
      ra[set][i] = *reinterpret_cast<const f32x4*>(xp + (size_t)(i * 32) * K_ + ks * 64);
      rb[set][i] = *reinterpret_cast<const f32x4*>(wp + (size_t)(i * 32) * K_ + ks * 64);
    }
  };
  auto STAGE = [&](int set, int buf) {
#pragma unroll
    for (int i = 0; i < 4; ++i) {
      ushort4 ha, hb;
      ha.x = f2bf(ra[set][i].x); ha.y = f2bf(ra[set][i].y);
      ha.z = f2bf(ra[set][i].z); ha.w = f2bf(ra[set][i].w);
      hb.x = f2bf(rb[set][i].x); hb.y = f2bf(rb[set][i].y);
      hb.z = f2bf(rb[set][i].z); hb.w = f2bf(rb[set][i].w);
      *reinterpret_cast<ushort4*>(&Asf[buf][(sr + 32 * i) * FLDSK + sc]) = ha;
      *reinterpret_cast<ushort4*>(&Bsf[buf][(sr + 32 * i) * FLDSK + sc]) = hb;
    }
  };
  auto MMA = [&](int buf) {
#pragma unroll
    for (int kk = 0; kk < 2; ++kk) {
      const int kof = kk * 32 + (lane >> 4) * 8;
      bf16x8 aa[4], bb[2];
#pragma unroll
      for (int mi = 0; mi < 4; ++mi)
        aa[mi] = *reinterpret_cast<const bf16x8*>(
            &Asf[buf][(wr * 64 + mi * 16 + (lane & 15)) * FLDSK + kof]);
#pragma unroll
      for (int ni = 0; ni < 2; ++ni)
        bb[ni] = *reinterpret_cast<const bf16x8*>(
            &Bsf[buf][(wc * 32 + ni * 16 + (lane & 15)) * FLDSK + kof]);
#pragma unroll
      for (int mi = 0; mi < 4; ++mi)
#pragma unroll
        for (int ni = 0; ni < 2; ++ni)
          acc[mi][ni] = __builtin_amdgcn_mfma_f32_16x16x32_bf16(aa[mi], bb[ni],
                                                                acc[mi][ni], 0, 0, 0);
    }
  };
  LOAD(0, 0); LOAD(1, 1); STAGE(0, 0);
  __syncthreads();
#pragma unroll
  for (int ks = 0; ks < FNKS - 1; ++ks) {
    if (ks + 2 < FNKS) LOAD(ks & 1, ks + 2);
    MMA(ks & 1);
    STAGE((ks + 1) & 1, (ks + 1) & 1);
    __syncthreads();
  }
  MMA((FNKS - 1) & 1);
  const int col0 = n0 + wc * 32 + (lane & 15);
  const int rsub = (lane >> 4) * 4;
#pragma unroll
  for (int mi = 0; mi < 4; ++mi)
#pragma unroll
    for (int ni = 0; ni < 2; ++ni)
#pragma unroll
      for (int r = 0; r < 4; ++r)
        C[(size_t)(m0 + wr * 64 + mi * 16 + rsub + r) * N_ + (col0 + ni * 16)] =
            acc[mi][ni][r];
}

extern "C" void kernel_launch(void* const* d_in, const int* in_sizes, int n_in,
                              void* d_out, int out_size, void* d_ws, size_t ws_size,
                              hipStream_t stream) {
  const float* x = (const float*)d_in[0];
  const float* w = (const float*)d_in[1];
  float* out = (float*)d_out;
  const int M = in_sizes[0] / K_;            // 32768
  if (ws_size >= (size_t)(512 * 1024)) {
    ushort* Wp = (ushort*)d_ws;
    pack_w<<<dim3(128), dim3(256), 0, stream>>>(w, Wp);
    dim3 grid(M / 64);                       // 512 blocks, 2 per CU
    gemm_pp<<<grid, dim3(256), 0, stream>>>(x, Wp, out);
  } else {
    dim3 grid((M / FBM) * (N_ / FBN));
    gemm_fb<<<grid, dim3(512), 0, stream>>>(x, w, out);
  }
}